// Round 5
// baseline (654.543 us; speedup 1.0000x reference)
//
#include <hip/hip_runtime.h>

// N=384 spatial, C=128 channels. Two tri-mul passes (outgoing, incoming).
// ws layout: [12 swizzled bf16 weight mats | a_t | b_t | g | zn/p_t(shared)],
// big bufs NN*128 bf16 each. Total ~144.4 MiB.
// p layout (tri -> out): [i][c][k]  (row-blob of 98KB per i, contiguous).

constexpr int NS = 384;
constexpr int NN = NS * NS;

using bf16x8 = __attribute__((ext_vector_type(8))) __bf16;
using f32x4  = __attribute__((ext_vector_type(4))) float;

__device__ inline void load16_to_lds(const __bf16* g, __bf16* lds) {
  auto* gp = reinterpret_cast<const __attribute__((address_space(1))) unsigned int*>(
      reinterpret_cast<uintptr_t>(g));
  auto* lp = reinterpret_cast<__attribute__((address_space(3))) unsigned int*>(
      reinterpret_cast<uintptr_t>(lds));
  __builtin_amdgcn_global_load_lds(gp, lp, 16, 0, 0);
}

__device__ inline float sigmoidf_fast(float x) {
  float e = __expf(-x);
  return __builtin_amdgcn_rcpf(1.0f + e);
}

// ---------------- K0: weight fp32 -> bf16, swizzled to MFMA fragment order ------------
__global__ __launch_bounds__(256) void prep_weights(
    const float* __restrict__ w_ag, const float* __restrict__ w_ap,
    const float* __restrict__ w_bg, const float* __restrict__ w_bp,
    const float* __restrict__ w_g,  const float* __restrict__ w_z,
    __bf16* __restrict__ wsw)
{
  int gid  = blockIdx.x * 256 + threadIdx.x;   // 96*256 = 24576 = 12*2048
  int mat  = gid >> 11;
  int slot = gid & 2047;
  int lane = slot & 63;
  int tb   = (slot >> 6) & 7;
  int s    = slot >> 9;
  int pass = mat / 6, which = mat % 6;
  const float* W;
  switch (which) {
    case 0: W = w_ag; break; case 1: W = w_ap; break; case 2: W = w_bg; break;
    case 3: W = w_bp; break; case 4: W = w_g;  break; default: W = w_z;
  }
  W += pass * 16384;
  int n0 = tb * 16 + (lane & 15);
  int k0 = s * 32 + (lane >> 4) * 8;
  __bf16* dst = wsw + ((size_t)mat * 2048 + slot) * 8;
#pragma unroll
  for (int j = 0; j < 8; ++j) dst[j] = (__bf16)W[(k0 + j) * 128 + n0];
}

// ---------------- K1: LayerNorm z -> zn bf16 ------------------------------------------
__global__ __launch_bounds__(256) void ln_kernel(
    const float* __restrict__ zsrc, const float* __restrict__ lnw, const float* __restrict__ lnb,
    __bf16* __restrict__ zn, int mode)
{
  int tid = threadIdx.x;
  int row = tid >> 2, q = tid & 3;
  size_t zoff, qidx;
  if (mode == 0) { qidx = (size_t)blockIdx.x * 64 + row; zoff = qidx * 128; }
  else {
    int i = blockIdx.x / 6;
    int j = (blockIdx.x % 6) * 64 + row;
    zoff = ((size_t)j * NS + i) * 128;
    qidx = (size_t)i * NS + j;
  }
  const float4* zp = (const float4*)(zsrc + zoff) + q * 8;
  float4 v[8];
#pragma unroll
  for (int u = 0; u < 8; ++u) v[u] = zp[u];
  float s1 = 0.f, s2 = 0.f;
#pragma unroll
  for (int u = 0; u < 8; ++u) {
    float4 t = v[u];
    s1 += t.x + t.y + t.z + t.w;
    s2 += t.x * t.x + t.y * t.y + t.z * t.z + t.w * t.w;
  }
  s1 += __shfl_xor(s1, 1); s2 += __shfl_xor(s2, 1);
  s1 += __shfl_xor(s1, 2); s2 += __shfl_xor(s2, 2);
  float mean = s1 * (1.0f / 128.0f);
  float var  = s2 * (1.0f / 128.0f) - mean * mean;
  float rstd = rsqrtf(var + 1e-5f);
  bf16x8 o[4];
#pragma unroll
  for (int u = 0; u < 8; ++u) {
    int c0 = q * 32 + u * 4;
    float4 t  = v[u];
    float4 w4 = *(const float4*)(lnw + c0);
    float4 b4 = *(const float4*)(lnb + c0);
    o[u >> 1][(u & 1) * 4 + 0] = (__bf16)((t.x - mean) * rstd * w4.x + b4.x);
    o[u >> 1][(u & 1) * 4 + 1] = (__bf16)((t.y - mean) * rstd * w4.y + b4.y);
    o[u >> 1][(u & 1) * 4 + 2] = (__bf16)((t.z - mean) * rstd * w4.z + b4.z);
    o[u >> 1][(u & 1) * 4 + 3] = (__bf16)((t.w - mean) * rstd * w4.w + b4.w);
  }
  __bf16* dst = zn + qidx * 128 + q * 32;
#pragma unroll
  for (int u = 0; u < 4; ++u) *(bf16x8*)(dst + u * 8) = o[u];
}

// ---------------- K2: projections, tile-looped + double-buffered ----------------------
__global__ __launch_bounds__(256, 3) void proj3_kernel(
    const __bf16* __restrict__ zn, const __bf16* __restrict__ wsw5,
    const float* __restrict__ bag, const float* __restrict__ bap,
    const float* __restrict__ bbg, const float* __restrict__ bbp,
    const float* __restrict__ bgg,
    __bf16* __restrict__ a_t, __bf16* __restrict__ b_t, __bf16* __restrict__ g_out,
    int mode)
{
  __shared__ __bf16 zl[2][64 * 128];   // 2 x 16 KB, swizzled: row r slot s = chunk s^(r&15)
  const int tid = threadIdx.x;
  const int wv = tid >> 6, lane = tid & 63;
  const int lm = lane & 15, lq = lane >> 4;
  const int id = blockIdx.x;
  const int prod = id / 288;
  const int grp  = id % 288;
  const bool twomat = (prod != 2);
  const __bf16* wbase = wsw5 + (size_t)prod * 2 * 16384;

  bf16x8 wf[2][2][4];
#pragma unroll
  for (int n2 = 0; n2 < 2; ++n2)
#pragma unroll
    for (int s = 0; s < 4; ++s) {
      wf[n2][0][s] = *(const bf16x8*)(wbase + ((size_t)((s * 8 + 2 * wv + n2) * 64 + lane)) * 8);
      if (twomat)
        wf[n2][1][s] = *(const bf16x8*)(wbase + 16384 + ((size_t)((s * 8 + 2 * wv + n2) * 64 + lane)) * 8);
    }
  const float* pbA = (prod == 0) ? bag : (prod == 1) ? bbg : bgg;
  const float* pbB = (prod == 0) ? bap : bbp;
  float bA[2] = {0.f, 0.f}, bB[2] = {0.f, 0.f};
  f32x4 bG[2];
#pragma unroll
  for (int n2 = 0; n2 < 2; ++n2) {
    if (twomat) {
      bA[n2] = pbA[(2 * wv + n2) * 16 + lm];
      bB[n2] = pbB[(2 * wv + n2) * 16 + lm];
    } else {
      bG[n2] = *(const f32x4*)(bgg + (2 * wv + n2) * 16 + 4 * lq);
    }
  }

  const int lrow = lane >> 4, lsl = lane & 15;
#define STAGE(T, BUF)                                                          \
  {                                                                            \
    const __bf16* src = zn + (size_t)(T) * 64 * 128;                           \
    _Pragma("unroll")                                                          \
    for (int t = 0; t < 4; ++t) {                                              \
      int rbase = wv * 16 + t * 4;                                             \
      int row = rbase + lrow;                                                  \
      int chunk = lsl ^ (row & 15);                                            \
      load16_to_lds(src + (size_t)row * 128 + chunk * 8, (BUF) + rbase * 128); \
    }                                                                          \
  }

  STAGE(grp * 8, zl[0]);

  for (int tt = 0; tt < 8; ++tt) {
    const int T = grp * 8 + tt;
    const __bf16* buf = zl[tt & 1];
    __syncthreads();
    if (tt < 7) STAGE(T + 1, zl[(tt & 1) ^ 1]);

    f32x4 acc[4][2][2];
#pragma unroll
    for (int m = 0; m < 4; ++m)
#pragma unroll
      for (int n2 = 0; n2 < 2; ++n2) {
        acc[m][n2][0] = {0.f, 0.f, 0.f, 0.f};
        acc[m][n2][1] = {0.f, 0.f, 0.f, 0.f};
      }

    const size_t Tbase = (size_t)T * 64;
    if (twomat) {
#pragma unroll
      for (int m = 0; m < 4; ++m) {
        bf16x8 zf[4];
#pragma unroll
        for (int s = 0; s < 4; ++s)
          zf[s] = *(const bf16x8*)(buf + (m * 16 + lm) * 128 + (((4 * s + lq) ^ lm) << 3));
#pragma unroll
        for (int s = 0; s < 4; ++s)
#pragma unroll
          for (int n2 = 0; n2 < 2; ++n2) {
            acc[m][n2][0] = __builtin_amdgcn_mfma_f32_16x16x32_bf16(zf[s], wf[n2][0][s], acc[m][n2][0], 0, 0, 0);
            acc[m][n2][1] = __builtin_amdgcn_mfma_f32_16x16x32_bf16(zf[s], wf[n2][1][s], acc[m][n2][1], 0, 0, 0);
          }
      }
      __bf16* outp = (prod == 0) ? a_t : b_t;
#pragma unroll
      for (int m = 0; m < 4; ++m)
#pragma unroll
        for (int n2 = 0; n2 < 2; ++n2) {
          int c = (2 * wv + n2) * 16 + lm;
          union { __bf16 h[4]; uint2 u; } pk;
#pragma unroll
          for (int r = 0; r < 4; ++r) {
            float gg = acc[m][n2][0][r] + bA[n2];
            float pp = acc[m][n2][1][r] + bB[n2];
            pk.h[r] = (__bf16)(pp * sigmoidf_fast(gg));
          }
          *(uint2*)(outp + (size_t)c * NN + Tbase + 16 * m + 4 * lq) = pk.u;
        }
    } else {
#pragma unroll
      for (int m = 0; m < 4; ++m) {
        bf16x8 zf[4];
#pragma unroll
        for (int s = 0; s < 4; ++s)
          zf[s] = *(const bf16x8*)(buf + (m * 16 + lm) * 128 + (((4 * s + lq) ^ lm) << 3));
#pragma unroll
        for (int s = 0; s < 4; ++s)
#pragma unroll
          for (int n2 = 0; n2 < 2; ++n2)
            acc[m][n2][0] = __builtin_amdgcn_mfma_f32_16x16x32_bf16(wf[n2][0][s], zf[s], acc[m][n2][0], 0, 0, 0);
      }
#pragma unroll
      for (int m = 0; m < 4; ++m)
#pragma unroll
        for (int n2 = 0; n2 < 2; ++n2) {
          size_t q = Tbase + 16 * m + lm;
          size_t gp;
          if (mode == 0) gp = q;
          else { int i = (int)(q / NS); int j = (int)(q % NS); gp = (size_t)j * NS + i; }
          int c0 = (2 * wv + n2) * 16 + 4 * lq;
          union { __bf16 h[4]; uint2 u; } pk;
#pragma unroll
          for (int r = 0; r < 4; ++r)
            pk.h[r] = (__bf16)sigmoidf_fast(acc[m][n2][0][r] + bG[n2][r]);
          *(uint2*)(g_out + gp * 128 + c0) = pk.u;
        }
    }
  }
#undef STAGE
}

// ---------------- K3: triangle einsum, per-channel 384x384x384 NT GEMM ----------------
// Writes p in [i][c][k] layout: addr = (i*128 + c)*384 + k  (row-blob contiguous for out).
__global__ __launch_bounds__(256) void tri_kernel(
    const __bf16* __restrict__ a_t, const __bf16* __restrict__ b_t, __bf16* __restrict__ p_t)
{
  __shared__ __bf16 As[128 * 64];
  __shared__ __bf16 Bs[128 * 64];
  int id = blockIdx.x;
  int xcd = id & 7;
  int k   = id >> 3;                 // 0..143
  int c   = ((k / 9) << 3) + xcd;    // channel 0..127
  int t   = k % 9;
  int i0 = (t / 3) * 128, k0 = (t % 3) * 128;
  const __bf16* Ab = a_t + (size_t)c * NN;
  const __bf16* Bb = b_t + (size_t)c * NN;
  int tid = threadIdx.x, wv = tid >> 6, lane = tid & 63;
  int lm = lane & 15, lq = lane >> 4;
  int lrow = lane >> 3;
  int lsl  = lane & 7;
  int lch  = lsl ^ lrow;
  f32x4 acc[4][4];
#pragma unroll
  for (int mi = 0; mi < 4; ++mi)
#pragma unroll
    for (int ni = 0; ni < 4; ++ni) acc[mi][ni] = {0.f, 0.f, 0.f, 0.f};
  const int rowA_half = 64 * (wv & 1), colB_half = 64 * (wv >> 1);

  for (int kk = 0; kk < 384; kk += 64) {
    __syncthreads();
#pragma unroll
    for (int v = 0; v < 4; ++v) {
      int rgrp = 4 * wv + v;
      int r = 8 * rgrp + lrow;
      load16_to_lds(Ab + (size_t)(i0 + r) * NS + kk + lch * 8, As + rgrp * 512);
      load16_to_lds(Bb + (size_t)(k0 + r) * NS + kk + lch * 8, Bs + rgrp * 512);
    }
    __syncthreads();
#pragma unroll
    for (int s = 0; s < 2; ++s) {
      bf16x8 bfr[4], afr[4];
#pragma unroll
      for (int ni = 0; ni < 4; ++ni)
        bfr[ni] = *(const bf16x8*)(Bs + (colB_half + 16 * ni + lm) * 64 +
                                   ((4 * s + lq) ^ (lm & 7)) * 8);
#pragma unroll
      for (int mi = 0; mi < 4; ++mi)
        afr[mi] = *(const bf16x8*)(As + (rowA_half + 16 * mi + lm) * 64 +
                                   ((4 * s + lq) ^ (lm & 7)) * 8);
#pragma unroll
      for (int mi = 0; mi < 4; ++mi)
#pragma unroll
        for (int ni = 0; ni < 4; ++ni)
          acc[mi][ni] = __builtin_amdgcn_mfma_f32_16x16x32_bf16(bfr[ni], afr[mi], acc[mi][ni], 0, 0, 0);
    }
  }
#pragma unroll
  for (int mi = 0; mi < 4; ++mi)
#pragma unroll
    for (int ni = 0; ni < 4; ++ni) {
      int row  = i0 + rowA_half + 16 * mi + lm;
      int colb = k0 + colB_half + 16 * ni + 4 * lq;
      union { __bf16 h[4]; uint2 u; } pk;
#pragma unroll
      for (int r = 0; r < 4; ++r) pk.h[r] = (__bf16)acc[mi][ni][r];
      *(uint2*)(p_t + ((size_t)row * 128 + c) * NS + colb) = pk.u;
    }
}

// ---------------- K4: LN over c, @w_z + b_z, * g, + z residual ------------------------
// Block = (row i, half of k): reads 49KB near-contiguous p row-blob, XOR-swizzled LDS
// transpose (4B packed channel pairs), LN (1 thread/row), mfma(wz, p) epilogue.
__global__ __launch_bounds__(256) void out_kernel(
    const __bf16* __restrict__ p_t, const __bf16* __restrict__ g_in,
    const float* __restrict__ z_in, float* __restrict__ z_out,
    const float* __restrict__ lnw, const float* __restrict__ lnb,
    const __bf16* __restrict__ wz, const float* __restrict__ bz)
{
  __shared__ __bf16 pl[192 * 128];   // 48 KB; row k slot s holds chunk s^(k&15)
  const int tid = threadIdx.x;
  const int i    = blockIdx.x >> 1;
  const int half = blockIdx.x & 1;
  const int kbase = half * 192;

  // ---- phase 1: read p[i][c][kbase+0..192), transpose into pl[k][c] ----
  {
    int pair = tid & 63, seg = tid >> 6;
    int c0 = 2 * pair;
    const __bf16* s0 = p_t + ((size_t)i * 128 + c0) * NS + kbase + seg * 48;
    const __bf16* s1 = s0 + NS;
    bf16x8 u0[6], u1[6];
#pragma unroll
    for (int u = 0; u < 6; ++u) { u0[u] = ((const bf16x8*)s0)[u]; u1[u] = ((const bf16x8*)s1)[u]; }
    int chunk = pair >> 2;
#pragma unroll
    for (int kk = 0; kk < 48; ++kk) {
      int k = seg * 48 + kk;
      union { __bf16 h[2]; unsigned w; } pk;
      pk.h[0] = u0[kk >> 3][kk & 7];
      pk.h[1] = u1[kk >> 3][kk & 7];
      int addr = k * 128 + ((chunk ^ (k & 15)) << 3) + (c0 & 7);
      *(unsigned*)(&pl[addr]) = pk.w;
    }
  }
  __syncthreads();

  // ---- phase 2: LayerNorm over c (1 thread per k-row, 192 active) ----
  if (tid < 192) {
    const int r = tid;
    bf16x8 pv[16];
#pragma unroll
    for (int j = 0; j < 16; ++j)
      pv[j] = *(const bf16x8*)(&pl[r * 128 + ((j ^ (r & 15)) << 3)]);
    float s1 = 0.f, s2 = 0.f;
#pragma unroll
    for (int j = 0; j < 16; ++j)
#pragma unroll
      for (int e = 0; e < 8; ++e) { float f = (float)pv[j][e]; s1 += f; s2 += f * f; }
    float mean = s1 * (1.0f / 128.0f);
    float var  = s2 * (1.0f / 128.0f) - mean * mean;
    float rstd = rsqrtf(var + 1e-5f);
#pragma unroll
    for (int j = 0; j < 16; ++j) {
#pragma unroll
      for (int e = 0; e < 8; ++e) {
        int cc = j * 8 + e;
        pv[j][e] = (__bf16)(((float)pv[j][e] - mean) * rstd * lnw[cc] + lnb[cc]);
      }
      *(bf16x8*)(&pl[r * 128 + ((j ^ (r & 15)) << 3)]) = pv[j];
    }
  }
  __syncthreads();

  // ---- phase 3: GEMM p_ln @ w_z; epilogue + b_z, * g, + z ----
  const int wv = tid >> 6, lane = tid & 63, lm = lane & 15, lq = lane >> 4;
  bf16x8 wzf[2][4];
#pragma unroll
  for (int nbi = 0; nbi < 2; ++nbi)
#pragma unroll
    for (int s = 0; s < 4; ++s)
      wzf[nbi][s] = *(const bf16x8*)(wz + ((size_t)((s * 8 + 2 * wv + nbi) * 64 + lane)) * 8);
#pragma unroll
  for (int mt = 0; mt < 12; ++mt) {
    bf16x8 af[4];
#pragma unroll
    for (int s = 0; s < 4; ++s)
      af[s] = *(const bf16x8*)(&pl[(16 * mt + lm) * 128 + (((4 * s + lq) ^ lm) << 3)]);
#pragma unroll
    for (int nbi = 0; nbi < 2; ++nbi) {
      f32x4 acc = {0.f, 0.f, 0.f, 0.f};
#pragma unroll
      for (int s = 0; s < 4; ++s)
        acc = __builtin_amdgcn_mfma_f32_16x16x32_bf16(wzf[nbi][s], af[s], acc, 0, 0, 0);
      int pos = 16 * mt + lm;
      int c0 = 16 * (2 * wv + nbi) + 4 * lq;
      size_t idx = ((size_t)i * NS + kbase + pos) * 128 + c0;
      float4 z4 = *(const float4*)(z_in + idx);
      float4 b4 = *(const float4*)(bz + c0);
      union { __bf16 h[4]; uint2 u; } gv;
      gv.u = *(const uint2*)(g_in + idx);
      float4 res;
      res.x = (acc[0] + b4.x) * (float)gv.h[0] + z4.x;
      res.y = (acc[1] + b4.y) * (float)gv.h[1] + z4.y;
      res.z = (acc[2] + b4.z) * (float)gv.h[2] + z4.z;
      res.w = (acc[3] + b4.w) * (float)gv.h[3] + z4.w;
      *(float4*)(z_out + idx) = res;
    }
  }
}

extern "C" void kernel_launch(void* const* d_in, const int* in_sizes, int n_in,
                              void* d_out, int out_size, void* d_ws, size_t ws_size,
                              hipStream_t stream) {
  (void)in_sizes; (void)n_in; (void)out_size; (void)ws_size;
  const float* z        = (const float*)d_in[0];
  const float* ln_in_w  = (const float*)d_in[1];
  const float* ln_in_b  = (const float*)d_in[2];
  const float* w_ag     = (const float*)d_in[3];
  const float* b_ag     = (const float*)d_in[4];
  const float* w_ap     = (const float*)d_in[5];
  const float* b_ap     = (const float*)d_in[6];
  const float* w_bg     = (const float*)d_in[7];
  const float* b_bg     = (const float*)d_in[8];
  const float* w_bp     = (const float*)d_in[9];
  const float* b_bp     = (const float*)d_in[10];
  const float* ln_out_w = (const float*)d_in[11];
  const float* ln_out_b = (const float*)d_in[12];
  const float* w_z      = (const float*)d_in[13];
  const float* b_z      = (const float*)d_in[14];
  const float* w_g      = (const float*)d_in[15];
  const float* b_g      = (const float*)d_in[16];
  float* out = (float*)d_out;

  __bf16* wsw  = (__bf16*)d_ws;             // 12 * 16384 elements
  __bf16* a_t  = wsw + 12 * 16384;
  __bf16* b_t  = a_t + (size_t)NN * 128;
  __bf16* g_b  = b_t + (size_t)NN * 128;
  __bf16* znpt = g_b + (size_t)NN * 128;    // zn during proj, p after tri

  prep_weights<<<96, 256, 0, stream>>>(w_ag, w_ap, w_bg, w_bp, w_g, w_z, wsw);

  for (int idx = 0; idx < 2; ++idx) {
    const float* zsrc = (idx == 0) ? z : out;
    const __bf16* wsw5 = wsw + (size_t)idx * 6 * 16384;
    ln_kernel<<<2304, 256, 0, stream>>>(zsrc, ln_in_w + idx * 128, ln_in_b + idx * 128,
                                        znpt, idx);
    proj3_kernel<<<864, 256, 0, stream>>>(
        znpt, wsw5,
        b_ag + idx * 128, b_ap + idx * 128, b_bg + idx * 128, b_bp + idx * 128,
        b_g + idx * 128, a_t, b_t, g_b, idx);
    tri_kernel<<<1152, 256, 0, stream>>>(a_t, b_t, znpt);
    out_kernel<<<768, 256, 0, stream>>>(
        znpt, g_b, zsrc, out, ln_out_w + idx * 128, ln_out_b + idx * 128,
        wsw5 + 5 * 16384, b_z + idx * 128);
  }
}